// Round 1
// baseline (1837.372 us; speedup 1.0000x reference)
//
#include <hip/hip_runtime.h>
#include <math.h>

#define N_NODES 100000
#define N_EDGES 1600000
#define HID     128
#define NGRAPH  256

// ============================= setup kernels =============================

__global__ void count_kernel(const int* __restrict__ ei, int* __restrict__ counts) {
    int e = blockIdx.x * 256 + threadIdx.x;
    if (e < N_EDGES) atomicAdd(&counts[ei[N_EDGES + e]], 1);
}

__global__ void dis_kernel(const int* __restrict__ counts, float* __restrict__ dis) {
    int i = blockIdx.x * 256 + threadIdx.x;
    if (i < N_NODES) dis[i] = rsqrtf((float)counts[i] + 1.0f);  // deg = in-count + self loop
}

// exclusive scan of counts -> offsets[N+1] and cursor copy. grid=2 (blockIdx = branch).
__global__ __launch_bounds__(1024) void scan_kernel(
        const int* __restrict__ c_sc, const int* __restrict__ c_fc,
        int* __restrict__ off_sc, int* __restrict__ off_fc,
        int* __restrict__ cur_sc, int* __restrict__ cur_fc) {
    const int* counts = blockIdx.x ? c_fc : c_sc;
    int* offs = blockIdx.x ? off_fc : off_sc;
    int* cur  = blockIdx.x ? cur_fc : cur_sc;
    __shared__ int lds[1024];
    int carry = 0;
    for (int base = 0; base < N_NODES; base += 1024) {
        int i = base + threadIdx.x;
        int v = (i < N_NODES) ? counts[i] : 0;
        lds[threadIdx.x] = v;
        __syncthreads();
        for (int off = 1; off < 1024; off <<= 1) {
            int t = (threadIdx.x >= off) ? lds[threadIdx.x - off] : 0;
            __syncthreads();
            lds[threadIdx.x] += t;
            __syncthreads();
        }
        int excl = carry + lds[threadIdx.x] - v;   // exclusive prefix
        if (i < N_NODES) { offs[i] = excl; cur[i] = excl; }
        carry += lds[1023];
        __syncthreads();
    }
    if (threadIdx.x == 0) offs[N_NODES] = carry;
}

__global__ void build_kernel(const int* __restrict__ ei, const float* __restrict__ dis,
                             int* __restrict__ cur, int* __restrict__ srcs,
                             float* __restrict__ en) {
    int e = blockIdx.x * 256 + threadIdx.x;
    if (e >= N_EDGES) return;
    int s = ei[e], d = ei[N_EDGES + e];
    int pos = atomicAdd(&cur[d], 1);
    srcs[pos] = s;
    en[pos] = dis[s] * dis[d];
}

// ============================= GEMM: C[N,128] = A[N,128] @ W[128,128] =============================
// block: 32 rows x 128 cols, 256 threads, 4x4 register tile. LDS 48KB -> 3 blocks/CU.
__global__ __launch_bounds__(256) void gemm128(const float* __restrict__ A,
                                               const float* __restrict__ W,
                                               float* __restrict__ C) {
    __shared__ float Alds[32 * 128];
    __shared__ float Wlds[64 * 128];
    const int tid = threadIdx.x;
    const int row0 = blockIdx.x * 32;
    {
        const float4* src = (const float4*)(A + (size_t)row0 * 128);
        float4* dst = (float4*)Alds;
#pragma unroll
        for (int i = 0; i < 4; ++i) dst[tid + i * 256] = src[tid + i * 256];
    }
    const int tc = (tid & 31) * 4;
    const int tr = (tid >> 5) * 4;
    float acc[4][4] = {};
    for (int kh = 0; kh < 2; ++kh) {
        __syncthreads();
        {
            const float4* src = (const float4*)(W + kh * 64 * 128);
            float4* dst = (float4*)Wlds;
#pragma unroll
            for (int i = 0; i < 8; ++i) dst[tid + i * 256] = src[tid + i * 256];
        }
        __syncthreads();
        for (int k = 0; k < 64; k += 4) {
            float a[4][4];
#pragma unroll
            for (int r = 0; r < 4; ++r)
                *(float4*)&a[r][0] = *(const float4*)&Alds[(tr + r) * 128 + kh * 64 + k];
#pragma unroll
            for (int kk = 0; kk < 4; ++kk) {
                float4 wv = *(const float4*)&Wlds[(k + kk) * 128 + tc];
#pragma unroll
                for (int r = 0; r < 4; ++r) {
                    float av = a[r][kk];
                    acc[r][0] += av * wv.x;
                    acc[r][1] += av * wv.y;
                    acc[r][2] += av * wv.z;
                    acc[r][3] += av * wv.w;
                }
            }
        }
    }
#pragma unroll
    for (int r = 0; r < 4; ++r)
        *(float4*)&C[(size_t)(row0 + tr + r) * 128 + tc] =
            make_float4(acc[r][0], acc[r][1], acc[r][2], acc[r][3]);
}

// ============================= GCN aggregation (CSR gather, no atomics) =============================
// x_out[n] = relu( h[n]*dis[n]^2 + b + sum_{e: dst==n} h[src_e]*enorm_e )
// one 32-lane group per node, each lane owns a float4 chunk of the 128 features.
__global__ __launch_bounds__(256) void gather_gcn(
        const float* __restrict__ h, const int* __restrict__ srcs,
        const float* __restrict__ en, const int* __restrict__ offs,
        const float* __restrict__ dis, const float* __restrict__ bias,
        float* __restrict__ xout) {
    int node = blockIdx.x * 8 + (threadIdx.x >> 5);
    if (node >= N_NODES) return;
    int lane = threadIdx.x & 31;
    int c = lane * 4;
    float d = dis[node];
    float sn = d * d;
    float4 hv = *(const float4*)&h[(size_t)node * 128 + c];
    float4 b4 = *(const float4*)&bias[c];
    float4 acc;
    acc.x = hv.x * sn + b4.x;
    acc.y = hv.y * sn + b4.y;
    acc.z = hv.z * sn + b4.z;
    acc.w = hv.w * sn + b4.w;
    int beg = offs[node], end = offs[node + 1];
    for (int j = beg; j < end; ++j) {
        int s = srcs[j];
        float w = en[j];
        float4 v = *(const float4*)&h[(size_t)s * 128 + c];
        acc.x += v.x * w;
        acc.y += v.y * w;
        acc.z += v.z * w;
        acc.w += v.w * w;
    }
    acc.x = fmaxf(acc.x, 0.f);
    acc.y = fmaxf(acc.y, 0.f);
    acc.z = fmaxf(acc.z, 0.f);
    acc.w = fmaxf(acc.w, 0.f);
    *(float4*)&xout[(size_t)node * 128 + c] = acc;
}

// ============================= pooling (batch is sorted) =============================
__global__ __launch_bounds__(128) void pool_kernel(const float* __restrict__ x,
                                                   const int* __restrict__ batch,
                                                   float* __restrict__ g) {
    int c = threadIdx.x;  // 0..127
    int start = blockIdx.x * 64;
    if (start >= N_NODES) return;
    int endn = min(start + 64, N_NODES);
    float acc = 0.f;
    int cur = batch[start];
    for (int i = start; i < endn; ++i) {
        int bb = batch[i];
        if (bb != cur) {
            atomicAdd(&g[(size_t)cur * 128 + c], acc);
            acc = 0.f;
            cur = bb;
        }
        acc += x[(size_t)i * 128 + c];
    }
    atomicAdd(&g[(size_t)cur * 128 + c], acc);
}

// ============================= row L2-normalize =============================
__global__ __launch_bounds__(64) void normalize_kernel(const float* __restrict__ g_sc,
                                                       const float* __restrict__ g_fc,
                                                       float* __restrict__ n_sc,
                                                       float* __restrict__ n_fc) {
    int r = blockIdx.x & 255;
    const float* g = (blockIdx.x < 256) ? g_sc : g_fc;
    float* o = (blockIdx.x < 256) ? n_sc : n_fc;
    int c = threadIdx.x;
    float v0 = g[r * 128 + c], v1 = g[r * 128 + c + 64];
    float ss = v0 * v0 + v1 * v1;
#pragma unroll
    for (int off = 32; off; off >>= 1) ss += __shfl_xor(ss, off);
    float inv = 1.0f / fmaxf(sqrtf(ss), 1e-12f);
    o[r * 128 + c] = v0 * inv;
    o[r * 128 + c + 64] = v1 * inv;
}

// ============================= classifier head: z=relu(cat@W1+b1); logp=log_softmax(z@W2+b2) =============================
__global__ __launch_bounds__(128) void head_kernel(const float* __restrict__ g_sc,
                                                   const float* __restrict__ g_fc,
                                                   const float* __restrict__ W1,
                                                   const float* __restrict__ b1,
                                                   const float* __restrict__ W2,
                                                   const float* __restrict__ b2,
                                                   float* __restrict__ out) {
    __shared__ float cat[256];
    __shared__ float red[4];
    int i = blockIdx.x, c = threadIdx.x;
    cat[c] = g_sc[i * 128 + c];
    cat[128 + c] = g_fc[i * 128 + c];
    __syncthreads();
    float acc = b1[c];
    for (int k = 0; k < 256; ++k) acc += cat[k] * W1[k * 128 + c];
    float z = fmaxf(acc, 0.f);
    float l0 = z * W2[c * 2 + 0];
    float l1 = z * W2[c * 2 + 1];
#pragma unroll
    for (int off = 32; off; off >>= 1) {
        l0 += __shfl_xor(l0, off);
        l1 += __shfl_xor(l1, off);
    }
    if ((c & 63) == 0) {
        red[(c >> 6) * 2 + 0] = l0;
        red[(c >> 6) * 2 + 1] = l1;
    }
    __syncthreads();
    if (c == 0) {
        float L0 = red[0] + red[2] + b2[0];
        float L1 = red[1] + red[3] + b2[1];
        float m = fmaxf(L0, L1);
        float lse = m + logf(expf(L0 - m) + expf(L1 - m));
        out[i * 2 + 0] = L0 - lse;
        out[i * 2 + 1] = L1 - lse;
    }
}

// ============================= contrastive loss =============================
// grid 512: blocks 0..255 -> loss_i rows, 256..511 -> loss_t rows. Accumulate sum of all losses.
__global__ __launch_bounds__(256) void contrast_kernel(const float* __restrict__ n_sc,
                                                       const float* __restrict__ n_fc,
                                                       float* __restrict__ loss_acc) {
    __shared__ float arow[128];
    __shared__ float redm[4];
    __shared__ float reds[4];
    __shared__ float diag_s;
    int b = blockIdx.x;
    int i = b & 255;
    bool which = b >= 256;
    const float* A  = which ? n_fc : n_sc;
    const float* B1 = which ? n_sc : n_fc;  // positive/cross block
    const float* B2 = which ? n_fc : n_sc;  // negative/self block
    int j = threadIdx.x;
    if (j < 128) arow[j] = A[i * 128 + j];
    __syncthreads();
    float d1 = 0.f, d2 = 0.f;
    for (int k = 0; k < 128; ++k) {
        float a = arow[k];
        d1 += a * B1[(size_t)j * 128 + k];
        d2 += a * B2[(size_t)j * 128 + k];
    }
    const float t = 2.0f;  // 1/TEMPERATURE
    float v1 = t * d1;
    float v2 = (j == i) ? 0.0f : 0.8f * t * d2;  // NEGATIVE_W * off_diag mask
    if (j == i) diag_s = v1;
    float m = fmaxf(v1, v2);
#pragma unroll
    for (int off = 32; off; off >>= 1) m = fmaxf(m, __shfl_xor(m, off));
    if ((j & 63) == 0) redm[j >> 6] = m;
    __syncthreads();
    m = fmaxf(fmaxf(redm[0], redm[1]), fmaxf(redm[2], redm[3]));
    float s = expf(v1 - m) + expf(v2 - m);
#pragma unroll
    for (int off = 32; off; off >>= 1) s += __shfl_xor(s, off);
    if ((j & 63) == 0) reds[j >> 6] = s;
    __syncthreads();
    if (j == 0) {
        float S = reds[0] + reds[1] + reds[2] + reds[3];
        float lse = m + logf(S);
        atomicAdd(loss_acc, lse - diag_s);
    }
}

__global__ void final_add(float* __restrict__ out, const float* __restrict__ loss) {
    int t = threadIdx.x;
    if (t < 512) out[t] += loss[0] * (1.0f / 512.0f);
}

// ============================= launch =============================

extern "C" void kernel_launch(void* const* d_in, const int* in_sizes, int n_in,
                              void* d_out, int out_size, void* d_ws, size_t ws_size,
                              hipStream_t stream) {
    const float* sc_x  = (const float*)d_in[0];
    const float* fc_x  = (const float*)d_in[1];
    const int*   sc_ei = (const int*)d_in[2];
    const int*   fc_ei = (const int*)d_in[3];
    const int*   batch = (const int*)d_in[4];
    const float* sc_W  = (const float*)d_in[5];
    const float* sc_b  = (const float*)d_in[6];
    const float* fc_W  = (const float*)d_in[7];
    const float* fc_b  = (const float*)d_in[8];
    const float* fc1_W = (const float*)d_in[9];
    const float* fc1_b = (const float*)d_in[10];
    const float* fc2_W = (const float*)d_in[11];
    const float* fc2_b = (const float*)d_in[12];
    float* out = (float*)d_out;

    const size_t NF = (size_t)N_NODES * HID;  // 12.8M floats

    float* ws = (float*)d_ws;
    float* x_sc  = ws;            // NF
    float* x_fc  = x_sc + NF;     // NF
    float* h     = x_fc + NF;     // NF (shared scratch between branches)
    float* en_sc = h + NF;        // E
    float* en_fc = en_sc + N_EDGES;
    float* dis_sc = en_fc + N_EDGES;  // N
    float* dis_fc = dis_sc + N_NODES;
    float* g_sc  = dis_fc + N_NODES;  // 32768 (g_sc,g_fc contiguous for one memset)
    float* g_fc  = g_sc + NGRAPH * HID;
    float* n_sc  = g_fc + NGRAPH * HID;
    float* n_fc  = n_sc + NGRAPH * HID;
    float* lossp = n_fc + NGRAPH * HID;  // 1 (+pad to 16B)
    int* srcs_sc   = (int*)(lossp + 4);  // E
    int* srcs_fc   = srcs_sc + N_EDGES;
    int* counts_sc = srcs_fc + N_EDGES;  // N
    int* counts_fc = counts_sc + N_NODES;
    int* off_sc    = counts_fc + N_NODES;  // N+1
    int* off_fc    = off_sc + (N_NODES + 1);
    int* cur_sc    = off_fc + (N_NODES + 1);  // N
    int* cur_fc    = cur_sc + N_NODES;
    (void)ws_size; (void)n_in; (void)in_sizes; (void)out_size;

    const int EB = (N_EDGES + 255) / 256;   // 6250
    const int NB = (N_NODES + 255) / 256;   // 391

    // ---- CSR build (per branch, once) ----
    hipMemsetAsync(counts_sc, 0, 2 * N_NODES * sizeof(int), stream);  // counts_sc+counts_fc contiguous
    count_kernel<<<EB, 256, 0, stream>>>(sc_ei, counts_sc);
    count_kernel<<<EB, 256, 0, stream>>>(fc_ei, counts_fc);
    dis_kernel<<<NB, 256, 0, stream>>>(counts_sc, dis_sc);
    dis_kernel<<<NB, 256, 0, stream>>>(counts_fc, dis_fc);
    scan_kernel<<<2, 1024, 0, stream>>>(counts_sc, counts_fc, off_sc, off_fc, cur_sc, cur_fc);
    build_kernel<<<EB, 256, 0, stream>>>(sc_ei, dis_sc, cur_sc, srcs_sc, en_sc);
    build_kernel<<<EB, 256, 0, stream>>>(fc_ei, dis_fc, cur_fc, srcs_fc, en_fc);

    // ---- initial features ----
    hipMemcpyAsync(x_sc, sc_x, NF * sizeof(float), hipMemcpyDeviceToDevice, stream);
    hipMemcpyAsync(x_fc, fc_x, NF * sizeof(float), hipMemcpyDeviceToDevice, stream);

    // ---- 3 GCN layers per branch ----
    for (int l = 0; l < 3; ++l) {
        gemm128<<<N_NODES / 32, 256, 0, stream>>>(x_sc, sc_W + (size_t)l * HID * HID, h);
        gather_gcn<<<N_NODES / 8, 256, 0, stream>>>(h, srcs_sc, en_sc, off_sc, dis_sc,
                                                    sc_b + (size_t)l * HID, x_sc);
        gemm128<<<N_NODES / 32, 256, 0, stream>>>(x_fc, fc_W + (size_t)l * HID * HID, h);
        gather_gcn<<<N_NODES / 8, 256, 0, stream>>>(h, srcs_fc, en_fc, off_fc, dis_fc,
                                                    fc_b + (size_t)l * HID, x_fc);
    }

    // ---- pooling ----
    hipMemsetAsync(g_sc, 0, 2 * NGRAPH * HID * sizeof(float), stream);
    const int PB = (N_NODES + 63) / 64;  // 1563
    pool_kernel<<<PB, 128, 0, stream>>>(x_sc, batch, g_sc);
    pool_kernel<<<PB, 128, 0, stream>>>(x_fc, batch, g_fc);

    // ---- head + contrastive ----
    normalize_kernel<<<512, 64, 0, stream>>>(g_sc, g_fc, n_sc, n_fc);
    head_kernel<<<NGRAPH, 128, 0, stream>>>(g_sc, g_fc, fc1_W, fc1_b, fc2_W, fc2_b, out);
    hipMemsetAsync(lossp, 0, sizeof(float), stream);
    contrast_kernel<<<512, 256, 0, stream>>>(n_sc, n_fc, lossp);
    final_add<<<1, 512, 0, stream>>>(out, lossp);
}

// Round 2
// 1503.361 us; speedup vs baseline: 1.2222x; 1.2222x over previous
//
#include <hip/hip_runtime.h>
#include <math.h>

#define N_NODES 100000
#define N_EDGES 1600000
#define HID     128
#define NGRAPH  256
#define SCHUNK  1024
#define NCHUNK  ((N_NODES + SCHUNK - 1) / SCHUNK)   // 98

typedef unsigned short u16;

__device__ inline float b2f(u16 u) {
    union { unsigned int i; float f; } x; x.i = ((unsigned int)u) << 16; return x.f;
}
__device__ inline u16 f2b(float f) {
    union { float f; unsigned int i; } x; x.f = f;
    unsigned int r = x.i + 0x7fff + ((x.i >> 16) & 1);   // round-to-nearest-even
    return (u16)(r >> 16);
}

// ============================= setup kernels =============================

__global__ void count_kernel(const int* __restrict__ ei, int* __restrict__ counts) {
    int e = blockIdx.x * 256 + threadIdx.x;
    if (e < N_EDGES) atomicAdd(&counts[ei[N_EDGES + e]], 1);
}

__global__ void dis_kernel(const int* __restrict__ counts, float* __restrict__ dis) {
    int i = blockIdx.x * 256 + threadIdx.x;
    if (i < N_NODES) dis[i] = rsqrtf((float)counts[i] + 1.0f);  // deg = in-count + self loop
}

// ---- 3-phase multi-block exclusive scan (both branches in one grid) ----
__global__ __launch_bounds__(256) void block_sum_kernel(const int* __restrict__ c_sc,
                                                        const int* __restrict__ c_fc,
                                                        int* __restrict__ bsum) {
    int branch = blockIdx.x / NCHUNK;
    int chunk  = blockIdx.x % NCHUNK;
    const int* counts = branch ? c_fc : c_sc;
    int base = chunk * SCHUNK;
    int tid = threadIdx.x;
    int v = 0;
    for (int i = tid; i < SCHUNK; i += 256) {
        int idx = base + i;
        if (idx < N_NODES) v += counts[idx];
    }
    __shared__ int red[4];
#pragma unroll
    for (int off = 32; off; off >>= 1) v += __shfl_down(v, off);
    if ((tid & 63) == 0) red[tid >> 6] = v;
    __syncthreads();
    if (tid == 0) bsum[blockIdx.x] = red[0] + red[1] + red[2] + red[3];
}

__global__ __launch_bounds__(256) void scan_tops_kernel(int* __restrict__ bsum) {
    __shared__ int lds[2][128];
    int tid = threadIdx.x;
    int branch = tid >> 7;
    int i = tid & 127;
    int orig = (i < NCHUNK) ? bsum[branch * NCHUNK + i] : 0;
    lds[branch][i] = orig;
    __syncthreads();
    for (int off = 1; off < 128; off <<= 1) {
        int t = (i >= off) ? lds[branch][i - off] : 0;
        __syncthreads();
        lds[branch][i] += t;
        __syncthreads();
    }
    if (i < NCHUNK) bsum[branch * NCHUNK + i] = lds[branch][i] - orig;  // exclusive
}

__global__ __launch_bounds__(256) void scan_final_kernel(
        const int* __restrict__ c_sc, const int* __restrict__ c_fc,
        const int* __restrict__ bsum,
        int* __restrict__ off_sc, int* __restrict__ off_fc,
        int* __restrict__ cur_sc, int* __restrict__ cur_fc) {
    int branch = blockIdx.x / NCHUNK;
    int chunk  = blockIdx.x % NCHUNK;
    const int* counts = branch ? c_fc : c_sc;
    int* offs = branch ? off_fc : off_sc;
    int* cur  = branch ? cur_fc : cur_sc;
    int tid = threadIdx.x;
    int base = chunk * SCHUNK + tid * 4;
    int v[4], s = 0;
#pragma unroll
    for (int k = 0; k < 4; ++k) {
        int idx = base + k;
        v[k] = (idx < N_NODES) ? counts[idx] : 0;
        s += v[k];
    }
    __shared__ int lds[256];
    lds[tid] = s;
    __syncthreads();
    for (int off = 1; off < 256; off <<= 1) {
        int t = (tid >= off) ? lds[tid - off] : 0;
        __syncthreads();
        lds[tid] += t;
        __syncthreads();
    }
    int prefix = bsum[blockIdx.x] + lds[tid] - s;   // exclusive prefix for this thread's 4
#pragma unroll
    for (int k = 0; k < 4; ++k) {
        int idx = base + k;
        if (idx < N_NODES) { offs[idx] = prefix; cur[idx] = prefix; }
        prefix += v[k];
    }
    if (blockIdx.x == 0 && tid == 0) { off_sc[N_NODES] = N_EDGES; off_fc[N_NODES] = N_EDGES; }
}

__global__ void build_kernel(const int* __restrict__ ei, const float* __restrict__ dis,
                             int* __restrict__ cur, int* __restrict__ srcs,
                             float* __restrict__ en) {
    int e = blockIdx.x * 256 + threadIdx.x;
    if (e >= N_EDGES) return;
    int s = ei[e], d = ei[N_EDGES + e];
    int pos = atomicAdd(&cur[d], 1);
    srcs[pos] = s;
    en[pos] = dis[s] * dis[d];
}

// ============================= GEMM: H[N,128] = A[N,128] @ W[128,128], bf16 out =============================
// block: 32 rows x 128 cols, 256 threads, 4x4 register tile. LDS 48KB -> 3 blocks/CU.
__global__ __launch_bounds__(256) void gemm128(const float* __restrict__ A,
                                               const float* __restrict__ W,
                                               u16* __restrict__ H) {
    __shared__ float Alds[32 * 128];
    __shared__ float Wlds[64 * 128];
    const int tid = threadIdx.x;
    const int row0 = blockIdx.x * 32;
    {
        const float4* src = (const float4*)(A + (size_t)row0 * 128);
        float4* dst = (float4*)Alds;
#pragma unroll
        for (int i = 0; i < 4; ++i) dst[tid + i * 256] = src[tid + i * 256];
    }
    const int tc = (tid & 31) * 4;
    const int tr = (tid >> 5) * 4;
    float acc[4][4] = {};
    for (int kh = 0; kh < 2; ++kh) {
        __syncthreads();
        {
            const float4* src = (const float4*)(W + kh * 64 * 128);
            float4* dst = (float4*)Wlds;
#pragma unroll
            for (int i = 0; i < 8; ++i) dst[tid + i * 256] = src[tid + i * 256];
        }
        __syncthreads();
        for (int k = 0; k < 64; k += 4) {
            float a[4][4];
#pragma unroll
            for (int r = 0; r < 4; ++r)
                *(float4*)&a[r][0] = *(const float4*)&Alds[(tr + r) * 128 + kh * 64 + k];
#pragma unroll
            for (int kk = 0; kk < 4; ++kk) {
                float4 wv = *(const float4*)&Wlds[(k + kk) * 128 + tc];
#pragma unroll
                for (int r = 0; r < 4; ++r) {
                    float av = a[r][kk];
                    acc[r][0] += av * wv.x;
                    acc[r][1] += av * wv.y;
                    acc[r][2] += av * wv.z;
                    acc[r][3] += av * wv.w;
                }
            }
        }
    }
#pragma unroll
    for (int r = 0; r < 4; ++r) {
        ushort4 o;
        o.x = f2b(acc[r][0]); o.y = f2b(acc[r][1]);
        o.z = f2b(acc[r][2]); o.w = f2b(acc[r][3]);
        *(ushort4*)&H[(size_t)(row0 + tr + r) * 128 + tc] = o;
    }
}

// ============================= GCN aggregation (CSR gather over bf16 h) =============================
// x_out[n] = relu( h[n]*dis[n]^2 + b + sum_{e: dst==n} h[src_e]*enorm_e ), fp32 accumulate
__global__ __launch_bounds__(256) void gather_gcn(
        const u16* __restrict__ h, const int* __restrict__ srcs,
        const float* __restrict__ en, const int* __restrict__ offs,
        const float* __restrict__ dis, const float* __restrict__ bias,
        float* __restrict__ xout) {
    int node = blockIdx.x * 8 + (threadIdx.x >> 5);
    if (node >= N_NODES) return;
    int lane = threadIdx.x & 31;
    int c = lane * 4;
    float d = dis[node];
    float sn = d * d;
    ushort4 hv = *(const ushort4*)&h[(size_t)node * 128 + c];
    float4 b4 = *(const float4*)&bias[c];
    float4 acc;
    acc.x = b2f(hv.x) * sn + b4.x;
    acc.y = b2f(hv.y) * sn + b4.y;
    acc.z = b2f(hv.z) * sn + b4.z;
    acc.w = b2f(hv.w) * sn + b4.w;
    int beg = offs[node], end = offs[node + 1];
    for (int j = beg; j < end; ++j) {
        int s = srcs[j];
        float w = en[j];
        ushort4 v = *(const ushort4*)&h[(size_t)s * 128 + c];
        acc.x += b2f(v.x) * w;
        acc.y += b2f(v.y) * w;
        acc.z += b2f(v.z) * w;
        acc.w += b2f(v.w) * w;
    }
    acc.x = fmaxf(acc.x, 0.f);
    acc.y = fmaxf(acc.y, 0.f);
    acc.z = fmaxf(acc.z, 0.f);
    acc.w = fmaxf(acc.w, 0.f);
    *(float4*)&xout[(size_t)node * 128 + c] = acc;
}

// ============================= pooling (batch is sorted) =============================
__global__ __launch_bounds__(128) void pool_kernel(const float* __restrict__ x,
                                                   const int* __restrict__ batch,
                                                   float* __restrict__ g) {
    int c = threadIdx.x;  // 0..127
    int start = blockIdx.x * 64;
    if (start >= N_NODES) return;
    int endn = min(start + 64, N_NODES);
    float acc = 0.f;
    int cur = batch[start];
    for (int i = start; i < endn; ++i) {
        int bb = batch[i];
        if (bb != cur) {
            atomicAdd(&g[(size_t)cur * 128 + c], acc);
            acc = 0.f;
            cur = bb;
        }
        acc += x[(size_t)i * 128 + c];
    }
    atomicAdd(&g[(size_t)cur * 128 + c], acc);
}

// ============================= row L2-normalize =============================
__global__ __launch_bounds__(64) void normalize_kernel(const float* __restrict__ g_sc,
                                                       const float* __restrict__ g_fc,
                                                       float* __restrict__ n_sc,
                                                       float* __restrict__ n_fc) {
    int r = blockIdx.x & 255;
    const float* g = (blockIdx.x < 256) ? g_sc : g_fc;
    float* o = (blockIdx.x < 256) ? n_sc : n_fc;
    int c = threadIdx.x;
    float v0 = g[r * 128 + c], v1 = g[r * 128 + c + 64];
    float ss = v0 * v0 + v1 * v1;
#pragma unroll
    for (int off = 32; off; off >>= 1) ss += __shfl_xor(ss, off);
    float inv = 1.0f / fmaxf(sqrtf(ss), 1e-12f);
    o[r * 128 + c] = v0 * inv;
    o[r * 128 + c + 64] = v1 * inv;
}

// ============================= classifier head =============================
__global__ __launch_bounds__(128) void head_kernel(const float* __restrict__ g_sc,
                                                   const float* __restrict__ g_fc,
                                                   const float* __restrict__ W1,
                                                   const float* __restrict__ b1,
                                                   const float* __restrict__ W2,
                                                   const float* __restrict__ b2,
                                                   float* __restrict__ out) {
    __shared__ float cat[256];
    __shared__ float red[4];
    int i = blockIdx.x, c = threadIdx.x;
    cat[c] = g_sc[i * 128 + c];
    cat[128 + c] = g_fc[i * 128 + c];
    __syncthreads();
    float acc = b1[c];
    for (int k = 0; k < 256; ++k) acc += cat[k] * W1[k * 128 + c];
    float z = fmaxf(acc, 0.f);
    float l0 = z * W2[c * 2 + 0];
    float l1 = z * W2[c * 2 + 1];
#pragma unroll
    for (int off = 32; off; off >>= 1) {
        l0 += __shfl_xor(l0, off);
        l1 += __shfl_xor(l1, off);
    }
    if ((c & 63) == 0) {
        red[(c >> 6) * 2 + 0] = l0;
        red[(c >> 6) * 2 + 1] = l1;
    }
    __syncthreads();
    if (c == 0) {
        float L0 = red[0] + red[2] + b2[0];
        float L1 = red[1] + red[3] + b2[1];
        float m = fmaxf(L0, L1);
        float lse = m + logf(expf(L0 - m) + expf(L1 - m));
        out[i * 2 + 0] = L0 - lse;
        out[i * 2 + 1] = L1 - lse;
    }
}

// ============================= contrastive loss =============================
__global__ __launch_bounds__(256) void contrast_kernel(const float* __restrict__ n_sc,
                                                       const float* __restrict__ n_fc,
                                                       float* __restrict__ loss_acc) {
    __shared__ float arow[128];
    __shared__ float redm[4];
    __shared__ float reds[4];
    __shared__ float diag_s;
    int b = blockIdx.x;
    int i = b & 255;
    bool which = b >= 256;
    const float* A  = which ? n_fc : n_sc;
    const float* B1 = which ? n_sc : n_fc;
    const float* B2 = which ? n_fc : n_sc;
    int j = threadIdx.x;
    if (j < 128) arow[j] = A[i * 128 + j];
    __syncthreads();
    float d1 = 0.f, d2 = 0.f;
    for (int k = 0; k < 128; ++k) {
        float a = arow[k];
        d1 += a * B1[(size_t)j * 128 + k];
        d2 += a * B2[(size_t)j * 128 + k];
    }
    const float t = 2.0f;  // 1/TEMPERATURE
    float v1 = t * d1;
    float v2 = (j == i) ? 0.0f : 0.8f * t * d2;
    if (j == i) diag_s = v1;
    float m = fmaxf(v1, v2);
#pragma unroll
    for (int off = 32; off; off >>= 1) m = fmaxf(m, __shfl_xor(m, off));
    if ((j & 63) == 0) redm[j >> 6] = m;
    __syncthreads();
    m = fmaxf(fmaxf(redm[0], redm[1]), fmaxf(redm[2], redm[3]));
    float s = expf(v1 - m) + expf(v2 - m);
#pragma unroll
    for (int off = 32; off; off >>= 1) s += __shfl_xor(s, off);
    if ((j & 63) == 0) reds[j >> 6] = s;
    __syncthreads();
    if (j == 0) {
        float S = reds[0] + reds[1] + reds[2] + reds[3];
        float lse = m + logf(S);
        atomicAdd(loss_acc, lse - diag_s);
    }
}

__global__ void final_add(float* __restrict__ out, const float* __restrict__ loss) {
    int t = threadIdx.x;
    if (t < 512) out[t] += loss[0] * (1.0f / 512.0f);
}

// ============================= launch =============================

extern "C" void kernel_launch(void* const* d_in, const int* in_sizes, int n_in,
                              void* d_out, int out_size, void* d_ws, size_t ws_size,
                              hipStream_t stream) {
    const float* sc_x  = (const float*)d_in[0];
    const float* fc_x  = (const float*)d_in[1];
    const int*   sc_ei = (const int*)d_in[2];
    const int*   fc_ei = (const int*)d_in[3];
    const int*   batch = (const int*)d_in[4];
    const float* sc_W  = (const float*)d_in[5];
    const float* sc_b  = (const float*)d_in[6];
    const float* fc_W  = (const float*)d_in[7];
    const float* fc_b  = (const float*)d_in[8];
    const float* fc1_W = (const float*)d_in[9];
    const float* fc1_b = (const float*)d_in[10];
    const float* fc2_W = (const float*)d_in[11];
    const float* fc2_b = (const float*)d_in[12];
    float* out = (float*)d_out;

    const size_t NF = (size_t)N_NODES * HID;  // 12.8M elements

    float* ws = (float*)d_ws;
    float* x_sc  = ws;                 // NF f32
    float* x_fc  = x_sc + NF;          // NF f32
    float* en_sc = x_fc + NF;          // E f32
    float* en_fc = en_sc + N_EDGES;
    float* dis_sc = en_fc + N_EDGES;   // N f32
    float* dis_fc = dis_sc + N_NODES;
    float* g_sc  = dis_fc + N_NODES;   // g_sc,g_fc contiguous for one memset
    float* g_fc  = g_sc + NGRAPH * HID;
    float* n_sc  = g_fc + NGRAPH * HID;
    float* n_fc  = n_sc + NGRAPH * HID;
    float* lossp = n_fc + NGRAPH * HID;  // 1 (+pad)
    u16* h       = (u16*)(lossp + 4);    // NF bf16 (shared between branches)
    int* srcs_sc   = (int*)(h + NF);     // E
    int* srcs_fc   = srcs_sc + N_EDGES;
    int* counts_sc = srcs_fc + N_EDGES;  // N (counts_sc+counts_fc contiguous)
    int* counts_fc = counts_sc + N_NODES;
    int* off_sc    = counts_fc + N_NODES;  // N+1
    int* off_fc    = off_sc + (N_NODES + 1);
    int* cur_sc    = off_fc + (N_NODES + 1);  // N
    int* cur_fc    = cur_sc + N_NODES;
    int* bsum      = cur_fc + N_NODES;        // 2*NCHUNK
    (void)ws_size; (void)n_in; (void)in_sizes; (void)out_size;

    const int EB = (N_EDGES + 255) / 256;   // 6250
    const int NB = (N_NODES + 255) / 256;   // 391

    // ---- CSR build (per branch, once) ----
    hipMemsetAsync(counts_sc, 0, 2 * N_NODES * sizeof(int), stream);
    count_kernel<<<EB, 256, 0, stream>>>(sc_ei, counts_sc);
    count_kernel<<<EB, 256, 0, stream>>>(fc_ei, counts_fc);
    dis_kernel<<<NB, 256, 0, stream>>>(counts_sc, dis_sc);
    dis_kernel<<<NB, 256, 0, stream>>>(counts_fc, dis_fc);
    block_sum_kernel<<<2 * NCHUNK, 256, 0, stream>>>(counts_sc, counts_fc, bsum);
    scan_tops_kernel<<<1, 256, 0, stream>>>(bsum);
    scan_final_kernel<<<2 * NCHUNK, 256, 0, stream>>>(counts_sc, counts_fc, bsum,
                                                      off_sc, off_fc, cur_sc, cur_fc);
    build_kernel<<<EB, 256, 0, stream>>>(sc_ei, dis_sc, cur_sc, srcs_sc, en_sc);
    build_kernel<<<EB, 256, 0, stream>>>(fc_ei, dis_fc, cur_fc, srcs_fc, en_fc);

    // ---- 3 GCN layers per branch (layer 0 reads inputs directly; no init copy) ----
    for (int l = 0; l < 3; ++l) {
        const float* a_sc = (l == 0) ? sc_x : x_sc;
        const float* a_fc = (l == 0) ? fc_x : x_fc;
        gemm128<<<N_NODES / 32, 256, 0, stream>>>(a_sc, sc_W + (size_t)l * HID * HID, h);
        gather_gcn<<<N_NODES / 8, 256, 0, stream>>>(h, srcs_sc, en_sc, off_sc, dis_sc,
                                                    sc_b + (size_t)l * HID, x_sc);
        gemm128<<<N_NODES / 32, 256, 0, stream>>>(a_fc, fc_W + (size_t)l * HID * HID, h);
        gather_gcn<<<N_NODES / 8, 256, 0, stream>>>(h, srcs_fc, en_fc, off_fc, dis_fc,
                                                    fc_b + (size_t)l * HID, x_fc);
    }

    // ---- pooling ----
    hipMemsetAsync(g_sc, 0, 2 * NGRAPH * HID * sizeof(float), stream);
    const int PB = (N_NODES + 63) / 64;  // 1563
    pool_kernel<<<PB, 128, 0, stream>>>(x_sc, batch, g_sc);
    pool_kernel<<<PB, 128, 0, stream>>>(x_fc, batch, g_fc);

    // ---- head + contrastive ----
    normalize_kernel<<<512, 64, 0, stream>>>(g_sc, g_fc, n_sc, n_fc);
    head_kernel<<<NGRAPH, 128, 0, stream>>>(g_sc, g_fc, fc1_W, fc1_b, fc2_W, fc2_b, out);
    hipMemsetAsync(lossp, 0, sizeof(float), stream);
    contrast_kernel<<<512, 256, 0, stream>>>(n_sc, n_fc, lossp);
    final_add<<<1, 512, 0, stream>>>(out, lossp);
}

// Round 3
// 1164.453 us; speedup vs baseline: 1.5779x; 1.2910x over previous
//
#include <hip/hip_runtime.h>
#include <math.h>

#define N_NODES 100000
#define N_EDGES 1600000
#define HID     128
#define NGRAPH  256
#define SCHUNK  1024
#define NCHUNK  ((N_NODES + SCHUNK - 1) / SCHUNK)   // 98
#define GB      ((N_NODES + 63) / 64)               // 1563 gemm blocks per branch
#define GAT_NB  (N_NODES / 4)                       // 25000 gather blocks per branch
#define EB      ((N_EDGES + 255) / 256)             // 6250
#define NB      ((N_NODES + 255) / 256)             // 391
#define PB      ((N_NODES + 63) / 64)               // 1563 pool blocks per branch

typedef unsigned short u16;
typedef __attribute__((ext_vector_type(8))) short    bf16x8;
typedef __attribute__((ext_vector_type(4))) float    f32x4;
typedef __attribute__((ext_vector_type(8))) unsigned short u16x8;

__device__ inline float b2f(u16 u) {
    union { unsigned int i; float f; } x; x.i = ((unsigned int)u) << 16; return x.f;
}
__device__ inline u16 f2b(float f) {
    union { float f; unsigned int i; } x; x.f = f;
    unsigned int r = x.i + 0x7fff + ((x.i >> 16) & 1);   // round-to-nearest-even
    return (u16)(r >> 16);
}

// ============================= setup kernels =============================

__global__ void count2_kernel(const int* __restrict__ sc_ei, const int* __restrict__ fc_ei,
                              int* __restrict__ c_sc, int* __restrict__ c_fc) {
    int b = blockIdx.x;
    const int* ei = (b >= EB) ? fc_ei : sc_ei;
    int* counts   = (b >= EB) ? c_fc  : c_sc;
    int e = (b >= EB ? b - EB : b) * 256 + threadIdx.x;
    if (e < N_EDGES) atomicAdd(&counts[ei[N_EDGES + e]], 1);
}

__global__ void dis2_kernel(const int* __restrict__ c_sc, const int* __restrict__ c_fc,
                            float* __restrict__ d_sc, float* __restrict__ d_fc) {
    int b = blockIdx.x;
    const int* counts = (b >= NB) ? c_fc : c_sc;
    float* dis        = (b >= NB) ? d_fc : d_sc;
    int i = (b >= NB ? b - NB : b) * 256 + threadIdx.x;
    if (i < N_NODES) dis[i] = rsqrtf((float)counts[i] + 1.0f);
}

// ---- 3-phase multi-block exclusive scan (both branches in one grid) ----
__global__ __launch_bounds__(256) void block_sum_kernel(const int* __restrict__ c_sc,
                                                        const int* __restrict__ c_fc,
                                                        int* __restrict__ bsum) {
    int branch = blockIdx.x / NCHUNK;
    int chunk  = blockIdx.x % NCHUNK;
    const int* counts = branch ? c_fc : c_sc;
    int base = chunk * SCHUNK;
    int tid = threadIdx.x;
    int v = 0;
    for (int i = tid; i < SCHUNK; i += 256) {
        int idx = base + i;
        if (idx < N_NODES) v += counts[idx];
    }
    __shared__ int red[4];
#pragma unroll
    for (int off = 32; off; off >>= 1) v += __shfl_down(v, off);
    if ((tid & 63) == 0) red[tid >> 6] = v;
    __syncthreads();
    if (tid == 0) bsum[blockIdx.x] = red[0] + red[1] + red[2] + red[3];
}

__global__ __launch_bounds__(256) void scan_tops_kernel(int* __restrict__ bsum) {
    __shared__ int lds[2][128];
    int tid = threadIdx.x;
    int branch = tid >> 7;
    int i = tid & 127;
    int orig = (i < NCHUNK) ? bsum[branch * NCHUNK + i] : 0;
    lds[branch][i] = orig;
    __syncthreads();
    for (int off = 1; off < 128; off <<= 1) {
        int t = (i >= off) ? lds[branch][i - off] : 0;
        __syncthreads();
        lds[branch][i] += t;
        __syncthreads();
    }
    if (i < NCHUNK) bsum[branch * NCHUNK + i] = lds[branch][i] - orig;  // exclusive
}

__global__ __launch_bounds__(256) void scan_final_kernel(
        const int* __restrict__ c_sc, const int* __restrict__ c_fc,
        const int* __restrict__ bsum,
        int* __restrict__ off_sc, int* __restrict__ off_fc,
        int* __restrict__ cur_sc, int* __restrict__ cur_fc) {
    int branch = blockIdx.x / NCHUNK;
    int chunk  = blockIdx.x % NCHUNK;
    const int* counts = branch ? c_fc : c_sc;
    int* offs = branch ? off_fc : off_sc;
    int* cur  = branch ? cur_fc : cur_sc;
    int tid = threadIdx.x;
    int base = chunk * SCHUNK + tid * 4;
    int v[4], s = 0;
#pragma unroll
    for (int k = 0; k < 4; ++k) {
        int idx = base + k;
        v[k] = (idx < N_NODES) ? counts[idx] : 0;
        s += v[k];
    }
    __shared__ int lds[256];
    lds[tid] = s;
    __syncthreads();
    for (int off = 1; off < 256; off <<= 1) {
        int t = (tid >= off) ? lds[tid - off] : 0;
        __syncthreads();
        lds[tid] += t;
        __syncthreads();
    }
    int prefix = bsum[blockIdx.x] + lds[tid] - s;
#pragma unroll
    for (int k = 0; k < 4; ++k) {
        int idx = base + k;
        if (idx < N_NODES) { offs[idx] = prefix; cur[idx] = prefix; }
        prefix += v[k];
    }
    if (blockIdx.x == 0 && tid == 0) { off_sc[N_NODES] = N_EDGES; off_fc[N_NODES] = N_EDGES; }
}

__global__ void build2_kernel(const int* __restrict__ sc_ei, const int* __restrict__ fc_ei,
                              const float* __restrict__ d_sc, const float* __restrict__ d_fc,
                              int* __restrict__ cur_sc, int* __restrict__ cur_fc,
                              int* __restrict__ srcs_sc, int* __restrict__ srcs_fc,
                              float* __restrict__ en_sc, float* __restrict__ en_fc) {
    int b = blockIdx.x;
    int branch = b >= EB;
    const int* ei   = branch ? fc_ei : sc_ei;
    const float* dis = branch ? d_fc : d_sc;
    int* cur  = branch ? cur_fc : cur_sc;
    int* srcs = branch ? srcs_fc : srcs_sc;
    float* en = branch ? en_fc : en_sc;
    int e = (branch ? b - EB : b) * 256 + threadIdx.x;
    if (e >= N_EDGES) return;
    int s = ei[e], d = ei[N_EDGES + e];
    int pos = atomicAdd(&cur[d], 1);
    srcs[pos] = s;
    en[pos] = dis[s] * dis[d];
}

// ---- pre-convert+transpose weights: Wt[l'][n][k] = W[l][k][n] (bf16), l' = branch*3+l ----
__global__ void convert_w_kernel(const float* __restrict__ sc_W, const float* __restrict__ fc_W,
                                 u16* __restrict__ Wt) {
    int idx = blockIdx.x * 256 + threadIdx.x;  // 6*16384 total
    if (idx >= 6 * 16384) return;
    int lp = idx >> 14;
    int r = idx & 16383;
    int n = r >> 7, k = r & 127;
    const float* W = (lp >= 3) ? fc_W : sc_W;
    int l = (lp >= 3) ? lp - 3 : lp;
    Wt[idx] = f2b(W[(size_t)l * 16384 + k * 128 + n]);
}

// ============================= MFMA GEMM: H[N,128] = bf16(A[N,128]) @ W[128,128] =============================
// block = 256 threads (4 waves); tile 64 rows x 128 cols; whole W in LDS; fp32 A converted in staging.
__global__ __launch_bounds__(256) void gemm2_kernel(
        const float* __restrict__ A_sc, const float* __restrict__ A_fc,
        const u16* __restrict__ Wt, int layer,
        u16* __restrict__ H_sc, u16* __restrict__ H_fc) {
    int branch = blockIdx.x >= GB;
    int blk = branch ? blockIdx.x - GB : blockIdx.x;
    const float* A = branch ? A_fc : A_sc;
    u16* H = branch ? H_fc : H_sc;
    const u16* W = Wt + (((size_t)branch * 3 + layer) << 14);

    __shared__ u16 Alds[64 * 136];   // rows padded to 136 u16 (272 B, 16B-aligned)
    __shared__ u16 Wlds[128 * 136];  // Wt rows: n-major, k contiguous
    const int tid = threadIdx.x;
    const int row0 = blk * 64;

    // stage A (fp32 -> bf16): 2048 float4s
#pragma unroll
    for (int i = 0; i < 8; ++i) {
        int idx = tid + i * 256;
        int r = idx >> 5, f = idx & 31;
        int grow = row0 + r;
        float4 v = (grow < N_NODES) ? *(const float4*)&A[(size_t)grow * 128 + f * 4]
                                    : make_float4(0.f, 0.f, 0.f, 0.f);
        ushort4 o;
        o.x = f2b(v.x); o.y = f2b(v.y); o.z = f2b(v.z); o.w = f2b(v.w);
        *(ushort4*)&Alds[r * 136 + f * 4] = o;
    }
    // stage W: 2048 u16x8s
#pragma unroll
    for (int i = 0; i < 8; ++i) {
        int idx = tid + i * 256;
        int n = idx >> 4, f = idx & 15;
        *(u16x8*)&Wlds[n * 136 + f * 8] = *(const u16x8*)&W[n * 128 + f * 8];
    }
    __syncthreads();

    const int wv = tid >> 6;
    const int lane = tid & 63;
    const int m = lane & 15;       // row (A) / col (B) within 16-tile
    const int quad = lane >> 4;    // k-subchunk

    bf16x8 af[4];
#pragma unroll
    for (int kt = 0; kt < 4; ++kt)
        af[kt] = *(const bf16x8*)&Alds[(wv * 16 + m) * 136 + kt * 32 + quad * 8];

    f32x4 acc[8];
#pragma unroll
    for (int ct = 0; ct < 8; ++ct) { acc[ct][0] = 0.f; acc[ct][1] = 0.f; acc[ct][2] = 0.f; acc[ct][3] = 0.f; }

#pragma unroll
    for (int ct = 0; ct < 8; ++ct) {
#pragma unroll
        for (int kt = 0; kt < 4; ++kt) {
            bf16x8 bf = *(const bf16x8*)&Wlds[(ct * 16 + m) * 136 + kt * 32 + quad * 8];
            acc[ct] = __builtin_amdgcn_mfma_f32_16x16x32_bf16(af[kt], bf, acc[ct], 0, 0, 0);
        }
    }

    // epilogue: C/D layout col=lane&15, row=quad*4+reg -> LDS -> coalesced bf16 stores
#pragma unroll
    for (int ct = 0; ct < 8; ++ct)
#pragma unroll
        for (int r = 0; r < 4; ++r)
            Alds[(wv * 16 + quad * 4 + r) * 136 + ct * 16 + m] = f2b(acc[ct][r]);
    __syncthreads();
#pragma unroll
    for (int i = 0; i < 4; ++i) {
        int idx = i * 64 + lane;
        int r = idx >> 4, f = idx & 15;
        int grow = row0 + wv * 16 + r;
        if (grow < N_NODES)
            *(u16x8*)&H[(size_t)grow * 128 + f * 8] = *(const u16x8*)&Alds[(wv * 16 + r) * 136 + f * 8];
    }
}

// ============================= GCN aggregation: wave per node, 4 edge-loads in flight =============================
__global__ __launch_bounds__(256) void gather2_kernel(
        const u16* __restrict__ h_sc, const u16* __restrict__ h_fc,
        const int* __restrict__ srcs_sc, const int* __restrict__ srcs_fc,
        const float* __restrict__ en_sc, const float* __restrict__ en_fc,
        const int* __restrict__ off_sc, const int* __restrict__ off_fc,
        const float* __restrict__ d_sc, const float* __restrict__ d_fc,
        const float* __restrict__ b_sc, const float* __restrict__ b_fc,
        float* __restrict__ x_sc, float* __restrict__ x_fc) {
    int bb = blockIdx.x;
    int branch = bb >= GAT_NB;
    if (branch) bb -= GAT_NB;
    const u16* h    = branch ? h_fc : h_sc;
    const int* srcs = branch ? srcs_fc : srcs_sc;
    const float* en = branch ? en_fc : en_sc;
    const int* offs = branch ? off_fc : off_sc;
    const float* dis = branch ? d_fc : d_sc;
    const float* bias = branch ? b_fc : b_sc;
    float* xout = branch ? x_fc : x_sc;

    int node = bb * 4 + (threadIdx.x >> 6);
    if (node >= N_NODES) return;
    int lane = threadIdx.x & 63;
    int half = lane >> 5;           // which edge of a pair this half-wave owns
    int c = (lane & 31) * 4;        // feature chunk
    int beg = offs[node], end = offs[node + 1];
    float ax = 0.f, ay = 0.f, az = 0.f, aw = 0.f;
    int j = beg + half;
    // two edges in flight per half-wave => 4 per wave
    for (; j + 2 < end; j += 4) {
        int s0 = srcs[j], s1 = srcs[j + 2];
        float w0 = en[j], w1 = en[j + 2];
        ushort4 v0 = *(const ushort4*)&h[(size_t)s0 * 128 + c];
        ushort4 v1 = *(const ushort4*)&h[(size_t)s1 * 128 + c];
        ax += b2f(v0.x) * w0 + b2f(v1.x) * w1;
        ay += b2f(v0.y) * w0 + b2f(v1.y) * w1;
        az += b2f(v0.z) * w0 + b2f(v1.z) * w1;
        aw += b2f(v0.w) * w0 + b2f(v1.w) * w1;
    }
    if (j < end) {
        int s0 = srcs[j];
        float w0 = en[j];
        ushort4 v0 = *(const ushort4*)&h[(size_t)s0 * 128 + c];
        ax += b2f(v0.x) * w0;
        ay += b2f(v0.y) * w0;
        az += b2f(v0.z) * w0;
        aw += b2f(v0.w) * w0;
    }
    ax += __shfl_xor(ax, 32);
    ay += __shfl_xor(ay, 32);
    az += __shfl_xor(az, 32);
    aw += __shfl_xor(aw, 32);
    if (half == 0) {
        float d = dis[node], sn = d * d;
        ushort4 hv = *(const ushort4*)&h[(size_t)node * 128 + c];
        float4 b4 = *(const float4*)&bias[c];
        float4 o;
        o.x = fmaxf(ax + b2f(hv.x) * sn + b4.x, 0.f);
        o.y = fmaxf(ay + b2f(hv.y) * sn + b4.y, 0.f);
        o.z = fmaxf(az + b2f(hv.z) * sn + b4.z, 0.f);
        o.w = fmaxf(aw + b2f(hv.w) * sn + b4.w, 0.f);
        *(float4*)&xout[(size_t)node * 128 + c] = o;
    }
}

// ============================= pooling (batch is sorted) =============================
__global__ __launch_bounds__(128) void pool2_kernel(const float* __restrict__ x_sc,
                                                    const float* __restrict__ x_fc,
                                                    const int* __restrict__ batch,
                                                    float* __restrict__ g_sc,
                                                    float* __restrict__ g_fc) {
    int b = blockIdx.x;
    const float* x = (b >= PB) ? x_fc : x_sc;
    float* g       = (b >= PB) ? g_fc : g_sc;
    int blk = (b >= PB) ? b - PB : b;
    int c = threadIdx.x;
    int start = blk * 64;
    if (start >= N_NODES) return;
    int endn = min(start + 64, N_NODES);
    float acc = 0.f;
    int cur = batch[start];
    for (int i = start; i < endn; ++i) {
        int bb = batch[i];
        if (bb != cur) {
            atomicAdd(&g[(size_t)cur * 128 + c], acc);
            acc = 0.f;
            cur = bb;
        }
        acc += x[(size_t)i * 128 + c];
    }
    atomicAdd(&g[(size_t)cur * 128 + c], acc);
}

// ============================= row L2-normalize =============================
__global__ __launch_bounds__(64) void normalize_kernel(const float* __restrict__ g_sc,
                                                       const float* __restrict__ g_fc,
                                                       float* __restrict__ n_sc,
                                                       float* __restrict__ n_fc) {
    int r = blockIdx.x & 255;
    const float* g = (blockIdx.x < 256) ? g_sc : g_fc;
    float* o = (blockIdx.x < 256) ? n_sc : n_fc;
    int c = threadIdx.x;
    float v0 = g[r * 128 + c], v1 = g[r * 128 + c + 64];
    float ss = v0 * v0 + v1 * v1;
#pragma unroll
    for (int off = 32; off; off >>= 1) ss += __shfl_xor(ss, off);
    float inv = 1.0f / fmaxf(sqrtf(ss), 1e-12f);
    o[r * 128 + c] = v0 * inv;
    o[r * 128 + c + 64] = v1 * inv;
}

// ============================= classifier head =============================
__global__ __launch_bounds__(128) void head_kernel(const float* __restrict__ g_sc,
                                                   const float* __restrict__ g_fc,
                                                   const float* __restrict__ W1,
                                                   const float* __restrict__ b1,
                                                   const float* __restrict__ W2,
                                                   const float* __restrict__ b2,
                                                   float* __restrict__ out) {
    __shared__ float cat[256];
    __shared__ float red[4];
    int i = blockIdx.x, c = threadIdx.x;
    cat[c] = g_sc[i * 128 + c];
    cat[128 + c] = g_fc[i * 128 + c];
    __syncthreads();
    float acc = b1[c];
    for (int k = 0; k < 256; ++k) acc += cat[k] * W1[k * 128 + c];
    float z = fmaxf(acc, 0.f);
    float l0 = z * W2[c * 2 + 0];
    float l1 = z * W2[c * 2 + 1];
#pragma unroll
    for (int off = 32; off; off >>= 1) {
        l0 += __shfl_xor(l0, off);
        l1 += __shfl_xor(l1, off);
    }
    if ((c & 63) == 0) {
        red[(c >> 6) * 2 + 0] = l0;
        red[(c >> 6) * 2 + 1] = l1;
    }
    __syncthreads();
    if (c == 0) {
        float L0 = red[0] + red[2] + b2[0];
        float L1 = red[1] + red[3] + b2[1];
        float m = fmaxf(L0, L1);
        float lse = m + logf(expf(L0 - m) + expf(L1 - m));
        out[i * 2 + 0] = L0 - lse;
        out[i * 2 + 1] = L1 - lse;
    }
}

// ============================= contrastive loss =============================
__global__ __launch_bounds__(256) void contrast_kernel(const float* __restrict__ n_sc,
                                                       const float* __restrict__ n_fc,
                                                       float* __restrict__ loss_acc) {
    __shared__ float arow[128];
    __shared__ float redm[4];
    __shared__ float reds[4];
    __shared__ float diag_s;
    int b = blockIdx.x;
    int i = b & 255;
    bool which = b >= 256;
    const float* A  = which ? n_fc : n_sc;
    const float* B1 = which ? n_sc : n_fc;
    const float* B2 = which ? n_fc : n_sc;
    int j = threadIdx.x;
    if (j < 128) arow[j] = A[i * 128 + j];
    __syncthreads();
    float d1 = 0.f, d2 = 0.f;
    for (int k = 0; k < 128; ++k) {
        float a = arow[k];
        d1 += a * B1[(size_t)j * 128 + k];
        d2 += a * B2[(size_t)j * 128 + k];
    }
    const float t = 2.0f;  // 1/TEMPERATURE
    float v1 = t * d1;
    float v2 = (j == i) ? 0.0f : 0.8f * t * d2;
    if (j == i) diag_s = v1;
    float m = fmaxf(v1, v2);
#pragma unroll
    for (int off = 32; off; off >>= 1) m = fmaxf(m, __shfl_xor(m, off));
    if ((j & 63) == 0) redm[j >> 6] = m;
    __syncthreads();
    m = fmaxf(fmaxf(redm[0], redm[1]), fmaxf(redm[2], redm[3]));
    float s = expf(v1 - m) + expf(v2 - m);
#pragma unroll
    for (int off = 32; off; off >>= 1) s += __shfl_xor(s, off);
    if ((j & 63) == 0) reds[j >> 6] = s;
    __syncthreads();
    if (j == 0) {
        float S = reds[0] + reds[1] + reds[2] + reds[3];
        float lse = m + logf(S);
        atomicAdd(loss_acc, lse - diag_s);
    }
}

__global__ void final_add(float* __restrict__ out, const float* __restrict__ loss) {
    int t = threadIdx.x;
    if (t < 512) out[t] += loss[0] * (1.0f / 512.0f);
}

// ============================= launch =============================

extern "C" void kernel_launch(void* const* d_in, const int* in_sizes, int n_in,
                              void* d_out, int out_size, void* d_ws, size_t ws_size,
                              hipStream_t stream) {
    const float* sc_x  = (const float*)d_in[0];
    const float* fc_x  = (const float*)d_in[1];
    const int*   sc_ei = (const int*)d_in[2];
    const int*   fc_ei = (const int*)d_in[3];
    const int*   batch = (const int*)d_in[4];
    const float* sc_W  = (const float*)d_in[5];
    const float* sc_b  = (const float*)d_in[6];
    const float* fc_W  = (const float*)d_in[7];
    const float* fc_b  = (const float*)d_in[8];
    const float* fc1_W = (const float*)d_in[9];
    const float* fc1_b = (const float*)d_in[10];
    const float* fc2_W = (const float*)d_in[11];
    const float* fc2_b = (const float*)d_in[12];
    float* out = (float*)d_out;

    const size_t NF = (size_t)N_NODES * HID;  // 12.8M elements

    float* ws = (float*)d_ws;
    float* x_sc  = ws;                 // NF f32
    float* x_fc  = x_sc + NF;          // NF f32
    float* en_sc = x_fc + NF;          // E f32
    float* en_fc = en_sc + N_EDGES;
    float* dis_sc = en_fc + N_EDGES;   // N f32
    float* dis_fc = dis_sc + N_NODES;
    float* g_sc  = dis_fc + N_NODES;   // g_sc,g_fc contiguous for one memset
    float* g_fc  = g_sc + NGRAPH * HID;
    float* n_sc  = g_fc + NGRAPH * HID;
    float* n_fc  = n_sc + NGRAPH * HID;
    float* lossp = n_fc + NGRAPH * HID;  // 1 (+pad)
    u16* h_sc    = (u16*)(lossp + 4);    // NF bf16
    u16* h_fc    = h_sc + NF;            // NF bf16
    u16* Wtb     = h_fc + NF;            // 6*16384 bf16 (transposed weights)
    int* srcs_sc   = (int*)(Wtb + 6 * 16384);  // E
    int* srcs_fc   = srcs_sc + N_EDGES;
    int* counts_sc = srcs_fc + N_EDGES;  // N (contiguous pair for memset)
    int* counts_fc = counts_sc + N_NODES;
    int* off_sc    = counts_fc + N_NODES;  // N+1
    int* off_fc    = off_sc + (N_NODES + 1);
    int* cur_sc    = off_fc + (N_NODES + 1);  // N
    int* cur_fc    = cur_sc + N_NODES;
    int* bsum      = cur_fc + N_NODES;        // 2*NCHUNK
    (void)ws_size; (void)n_in; (void)in_sizes; (void)out_size;

    // ---- CSR build (per branch, once) ----
    hipMemsetAsync(counts_sc, 0, 2 * N_NODES * sizeof(int), stream);
    count2_kernel<<<2 * EB, 256, 0, stream>>>(sc_ei, fc_ei, counts_sc, counts_fc);
    dis2_kernel<<<2 * NB, 256, 0, stream>>>(counts_sc, counts_fc, dis_sc, dis_fc);
    block_sum_kernel<<<2 * NCHUNK, 256, 0, stream>>>(counts_sc, counts_fc, bsum);
    scan_tops_kernel<<<1, 256, 0, stream>>>(bsum);
    scan_final_kernel<<<2 * NCHUNK, 256, 0, stream>>>(counts_sc, counts_fc, bsum,
                                                      off_sc, off_fc, cur_sc, cur_fc);
    build2_kernel<<<2 * EB, 256, 0, stream>>>(sc_ei, fc_ei, dis_sc, dis_fc,
                                              cur_sc, cur_fc, srcs_sc, srcs_fc, en_sc, en_fc);
    convert_w_kernel<<<(6 * 16384 + 255) / 256, 256, 0, stream>>>(sc_W, fc_W, Wtb);

    // ---- 3 GCN layers, both branches per launch ----
    for (int l = 0; l < 3; ++l) {
        const float* a_sc = (l == 0) ? sc_x : x_sc;
        const float* a_fc = (l == 0) ? fc_x : x_fc;
        gemm2_kernel<<<2 * GB, 256, 0, stream>>>(a_sc, a_fc, Wtb, l, h_sc, h_fc);
        gather2_kernel<<<2 * GAT_NB, 256, 0, stream>>>(
            h_sc, h_fc, srcs_sc, srcs_fc, en_sc, en_fc, off_sc, off_fc,
            dis_sc, dis_fc, sc_b + (size_t)l * HID, fc_b + (size_t)l * HID, x_sc, x_fc);
    }

    // ---- pooling ----
    hipMemsetAsync(g_sc, 0, 2 * NGRAPH * HID * sizeof(float), stream);
    pool2_kernel<<<2 * PB, 128, 0, stream>>>(x_sc, x_fc, batch, g_sc, g_fc);

    // ---- head + contrastive ----
    normalize_kernel<<<512, 64, 0, stream>>>(g_sc, g_fc, n_sc, n_fc);
    head_kernel<<<NGRAPH, 128, 0, stream>>>(g_sc, g_fc, fc1_W, fc1_b, fc2_W, fc2_b, out);
    hipMemsetAsync(lossp, 0, sizeof(float), stream);
    contrast_kernel<<<512, 256, 0, stream>>>(n_sc, n_fc, lossp);
    final_add<<<1, 512, 0, stream>>>(out, lossp);
}